// Round 12
// baseline (255.935 us; speedup 1.0000x reference)
//
#include <hip/hip_runtime.h>

#define Dm 96
#define PL (Dm*Dm*Dm)               // 884736 elements per (b, ic) plane
#define ICn 16
#define OCn 16
#define HYPn 128
#define BSn 4
// K-packing: 15 groups of K=32. grp = ty*5 + g (ty = ky tap 0..2, g = 0..4).
// k_local = cl*16 + ic, cl in {0,1} -> (kz,kx) combo c = 2g+cl (c=9 is padding).
#define NG 15
#define FRAG_ELEMS (NG*64*8)        // 7680 bf16 per sample

// xT: bf16 [b][z:-1..96][y:-1..96][x:-1..96][16ic], 32B per point, zero halo.
#define XP 98
#define ROWB (XP*32)                // 3136
#define PLANEB (XP*ROWB)            // 307328
#define SAMPB ((size_t)XP*PLANEB)   // 30118144
#define XT_TOTAL ((size_t)4*SAMPB)  // 120472576

typedef float   f32x4  __attribute__((ext_vector_type(4)));
typedef __bf16  bf16x8 __attribute__((ext_vector_type(8)));

__device__ __forceinline__ unsigned short f2bf(float f) {
    unsigned u = __builtin_bit_cast(unsigned, f);
    u = (u + 0x7FFFu + ((u >> 16) & 1u)) >> 16;
    return (unsigned short)u;
}

// ---------------- fused pre-pass: transpose + hypernetwork ----------------
// blk (after +boff): 0..1535 transpose interior; 1536..1543 z-halo planes;
// 1544..1663 hyper_frag; 1664 bias. Fallback launches with boff=1544.
__global__ __launch_bounds__(256)
void prep_kernel(const float* __restrict__ x, char* __restrict__ xT,
                 const float* __restrict__ hyp, const float* __restrict__ Wk,
                 const float* __restrict__ bk, unsigned short* __restrict__ kwf,
                 const float* __restrict__ Wb, const float* __restrict__ bb,
                 float* __restrict__ bias, int boff)
{
    int blk = blockIdx.x + boff;
    int tid = threadIdx.x;

    if (blk < 1536) {
        int yq = blk & 3;
        int z  = (blk >> 2) % Dm;
        int b  = (blk >> 2) / Dm;
        char* xTp = xT + (size_t)b*SAMPB + (size_t)(z+1)*PLANEB;
        const float* xb = x + (size_t)b*ICn*PL + (size_t)z*Dm*Dm;

        // interior: 1152 tasks = 2 ic-halves * 24 rows * 24 x-quads
        for (int t = tid; t < 1152; t += 256) {
            int ich = t & 1;
            int r   = t >> 1;
            int q = r % 24, yy = r / 24;
            int y = yq*24 + yy;
            const float* g = xb + (size_t)(ich*8)*PL + y*Dm + 4*q;
            f32x4 ld[8];
#pragma unroll
            for (int ic = 0; ic < 8; ++ic)
                ld[ic] = *(const f32x4*)(g + (size_t)ic*PL);
            char* w = xTp + (size_t)(y+1)*ROWB + (size_t)(1 + 4*q)*32 + ich*16;
#pragma unroll
            for (int xi = 0; xi < 4; ++xi) {
                bf16x8 v;
#pragma unroll
                for (int e = 0; e < 8; ++e) v[e] = (__bf16)ld[e][xi];
                *(bf16x8*)(w + xi*32) = v;
            }
        }
        bf16x8 z8;
#pragma unroll
        for (int i = 0; i < 8; ++i) z8[i] = (__bf16)0.f;
        for (int t = tid; t < 96; t += 256) {          // x-halo zeros
            int half = t & 1, side = (t >> 1) & 1, yy = t >> 2;
            int y = yq*24 + yy;
            *(bf16x8*)(xTp + (size_t)(y+1)*ROWB + (size_t)(side ? 97 : 0)*32 + half*16) = z8;
        }
        if (yq == 0 || yq == 3) {                       // y-halo rows
            char* w0 = xTp + (size_t)(yq == 0 ? 0 : 97)*ROWB;
            for (int t = tid; t < XP*2; t += 256)
                *(bf16x8*)(w0 + (size_t)t*16) = z8;
        }
        return;
    }
    if (blk < 1544) {                                   // z-halo planes
        int idx = blk - 1536;
        int b = idx >> 1, zb = idx & 1;
        char* p = xT + (size_t)b*SAMPB + (size_t)(zb ? 97 : 0)*PLANEB;
        f32x4 z4 = {0.f,0.f,0.f,0.f};
        for (int i = tid; i < PLANEB/16; i += 256)
            *(f32x4*)(p + (size_t)i*16) = z4;
        return;
    }
    if (blk < 1664) {                                   // hyper_frag
        int t = (blk - 1544) * 256 + tid;               // < 30720
        int j    = t & 7;
        int lane = (t >> 3) & 63;
        int rest = t >> 9;
        int grp  = rest % NG;
        int b    = rest / NG;
        int oc = lane & 15, hi = lane >> 4;
        int ty = grp / 5, g = grp % 5;
        int cl = hi >> 1;
        int ic = (hi & 1) * 8 + j;
        int c  = 2 * g + cl;
        float acc = 0.f;
        if (c < 9) {
            int tz = c / 3, tx = c % 3;
            int r = (oc * ICn + ic) * 27 + (tz * 9 + ty * 3 + tx);
            const float4* w = (const float4*)(Wk + (long)r * HYPn);
            const float4* h = (const float4*)(hyp + (long)b * HYPn);
            acc = bk[r];
#pragma unroll
            for (int q = 0; q < HYPn / 4; ++q) {
                float4 a = h[q], cc = w[q];
                acc += a.x * cc.x + a.y * cc.y + a.z * cc.z + a.w * cc.w;
            }
        }
        kwf[t] = f2bf(acc);
        return;
    }
    if (tid < 64) {                                     // bias
        int b = tid >> 4, oc = tid & 15;
        const float4* w = (const float4*)(Wb + (long)oc * HYPn);
        const float4* h = (const float4*)(hyp + (long)b * HYPn);
        float acc = bb[oc];
#pragma unroll
        for (int q = 0; q < HYPn / 4; ++q) {
            float4 a = h[q], c = w[q];
            acc += a.x * c.x + a.y * c.y + a.z * c.z + a.w * c.w;
        }
        bias[tid] = acc;
    }
}

// ---------------- MFMA conv: direct L2-served global loads, no LDS -----------
// One 64-thread block = 1 wave, fully independent: handles 4 z-planes of a
// (8y x 16x, 16oc) column. B-fragments are direct 16B global loads from the
// padded xT layout (L2-resident window); 3-plane-deep static load pipeline.
#define YT 8
#define XT 16
#define YL 10
#define NZW 4

__global__ __launch_bounds__(64, 2)
void conv_l2_kernel(const char* __restrict__ xT, const unsigned short* __restrict__ kwf,
                    const float* __restrict__ bias, float* __restrict__ out)
{
    const int NU = BSn * (Dm/NZW) * (Dm/YT) * (Dm/XT);   // 4*24*12*6 = 6912
    int raw = blockIdx.x;
    int u = (raw & 7) * (NU/8) + (raw >> 3);             // XCD-contiguous chunks

    int tx = u % 6;  u /= 6;
    int ty = u % 12; u /= 12;
    int zq = u % 24;
    int b  = u / 24;
    int x0 = tx*XT, y0 = ty*YT, z0 = zq*NZW;

    int lane = threadIdx.x;

    // A fragments: load once for 4 z-planes, pin in VGPRs
    const unsigned short* kwb = kwf + (long)b * FRAG_ELEMS;
    f32x4 afr[NG];
#pragma unroll
    for (int grp = 0; grp < NG; ++grp) {
        afr[grp] = *(const f32x4*)(kwb + (grp * 64 + lane) * 8);
        asm volatile("" : "+v"(afr[grp]));
    }

    int n   = lane & 15;
    int hi  = lane >> 4;
    int cl  = hi >> 1;
    int ich = hi & 1;

    // per-lane byte offsets for the 5 combo-groups (within the z-window)
    unsigned vboff[5];
#pragma unroll
    for (int g = 0; g < 5; ++g) {
        int c = 2*g + cl;
        if (c > 8) c = 8;                    // pad combo -> safe addr (A is zero)
        vboff[g] = (unsigned)((c/3)*PLANEB + (n + (c%3))*32 + ich*16);
    }

    float4 bv = *(const float4*)(bias + b * OCn + hi * 4);

    // window base for z-plane z: point (z-1, y0-1, x0-1)
    const char* xw0 = xT + (size_t)b*SAMPB + (size_t)z0*PLANEB
                         + (size_t)y0*ROWB + (size_t)x0*32;

#pragma unroll 1
    for (int zi = 0; zi < NZW; ++zi) {
        const char* xw = xw0 + (size_t)zi*PLANEB;

        auto loadp = [&](int P, bf16x8* F) {
#pragma unroll
            for (int g = 0; g < 5; ++g)
                F[g] = *(const bf16x8*)(xw + vboff[g] + (unsigned)(P*ROWB));
        };

        f32x4 acc[YT];
#pragma unroll
        for (int yy = 0; yy < YT; ++yy) acc[yy] = (f32x4){0.f,0.f,0.f,0.f};

        bf16x8 Fa[5], Fb[5], Fc[5];
        loadp(0, Fa);
        loadp(1, Fb);

#pragma unroll
        for (int p = 0; p < YL; ++p) {
            bf16x8* cur = (p % 3 == 0) ? Fa : (p % 3 == 1) ? Fb : Fc;
            bf16x8* nx2 = (p % 3 == 0) ? Fc : (p % 3 == 1) ? Fa : Fb;   // slot (p+2)%3
            if (p + 2 < YL) loadp(p + 2, nx2);
#pragma unroll
            for (int tyk = 0; tyk < 3; ++tyk) {
                int yy = p - tyk;
                if (yy >= 0 && yy < YT) {
#pragma unroll
                    for (int g = 0; g < 5; ++g)
                        acc[yy] = __builtin_amdgcn_mfma_f32_16x16x32_bf16(
                            __builtin_bit_cast(bf16x8, afr[tyk*5 + g]), cur[g], acc[yy], 0, 0, 0);
                }
            }
        }

        int z = z0 + zi;
#pragma unroll
        for (int yy = 0; yy < YT; ++yy) {
            int yo = y0 + yy;
            long obase = ((((long)b * OCn + hi * 4) * Dm + z) * Dm + yo) * Dm + x0 + n;
#pragma unroll
            for (int r = 0; r < 4; ++r)
                out[obase + (long)r * PL] = acc[yy][r] + ((const float*)&bv)[r];
        }
    }
}

// ---------------- fallback conv (r6 structure, in-kernel staging) ------------
#define ZT 4
#define ZL 6
#define XL 18
#define SSTR 32
#define SPN (ZL*YL*XL)

__device__ constexpr int coff(int c) {
    return ((c / 3) * YL * XL + (c % 3)) * SSTR;
}

__global__ __launch_bounds__(256, 4)
void conv_fb_kernel(const float* __restrict__ x, const unsigned short* __restrict__ kwf,
                    const float* __restrict__ bias, float* __restrict__ out)
{
    __shared__ __align__(16) char smem[SPN*SSTR];

    const int NXT = Dm / XT, NYT = Dm / YT, NZT = Dm / ZT;    // 6, 12, 24
    int raw = blockIdx.x;
    int bid = (raw & 7) * ((BSn * NXT * NYT * NZT) / 8) + (raw >> 3);

    int txi = bid % NXT; bid /= NXT;
    int tyi = bid % NYT; bid /= NYT;
    int tzi = bid % NZT;
    int b   = bid / NZT;
    int x0 = txi * XT, y0 = tyi * YT, z0 = tzi * ZT;

    int tid  = threadIdx.x;
    int lane = tid & 63;
    int wz   = tid >> 6;

    const float* xb = x + (long)b * ICn * PL;

    for (int t = tid; t < 480; t += 256) {
        int xq  = t & 3;
        int ich = (t >> 2) & 1;
        int row = t >> 3;
        int ly = row % YL, lz = row / YL;
        int gz = z0 - 1 + lz, gy = y0 - 1 + ly;
        int gx = x0 + 4 * xq;
        bf16x8 v[4];
        if ((unsigned)gz < (unsigned)Dm && (unsigned)gy < (unsigned)Dm) {
            const float* g = xb + (long)(ich * 8) * PL + ((long)gz * Dm + gy) * Dm + gx;
#pragma unroll
            for (int q = 0; q < 8; ++q) {
                f32x4 p = *(const f32x4*)(g + (long)q * PL);
                v[0][q] = (__bf16)p.x; v[1][q] = (__bf16)p.y;
                v[2][q] = (__bf16)p.z; v[3][q] = (__bf16)p.w;
            }
        } else {
#pragma unroll
            for (int xi = 0; xi < 4; ++xi)
#pragma unroll
                for (int q = 0; q < 8; ++q) v[xi][q] = (__bf16)0.f;
        }
        int sp = (lz * YL + ly) * XL + (1 + 4 * xq);
#pragma unroll
        for (int xi = 0; xi < 4; ++xi)
            *(bf16x8*)(smem + (sp + xi) * SSTR + ich * 16) = v[xi];
    }
    for (int t = tid; t < 240; t += 256) {
        int s   = t & 1;
        int ich = (t >> 1) & 1;
        int row = t >> 2;
        int ly = row % YL, lz = row / YL;
        int gz = z0 - 1 + lz, gy = y0 - 1 + ly;
        int lx = s ? (XL - 1) : 0;
        int gx = x0 - 1 + lx;
        bf16x8 v;
        if ((unsigned)gz < (unsigned)Dm && (unsigned)gy < (unsigned)Dm &&
            (unsigned)gx < (unsigned)Dm) {
            const float* g = xb + (long)(ich * 8) * PL + ((long)gz * Dm + gy) * Dm + gx;
#pragma unroll
            for (int q = 0; q < 8; ++q) v[q] = (__bf16)g[(long)q * PL];
        } else {
#pragma unroll
            for (int q = 0; q < 8; ++q) v[q] = (__bf16)0.f;
        }
        int sp = (lz * YL + ly) * XL + lx;
        *(bf16x8*)(smem + sp * SSTR + ich * 16) = v;
    }

    const unsigned short* kwb = kwf + (long)b * FRAG_ELEMS;
    f32x4 afr[NG];
#pragma unroll
    for (int grp = 0; grp < NG; ++grp) {
        afr[grp] = *(const f32x4*)(kwb + (grp * 64 + lane) * 8);
        asm volatile("" : "+v"(afr[grp]));
    }

    __syncthreads();

    int n   = lane & 15;
    int hi  = lane >> 4;
    int cl  = hi >> 1;
    int ich = hi & 1;

    int addr_g[5];
#pragma unroll
    for (int g = 0; g < 5; ++g) {
        int c = 2 * g + cl;
        if (c > 8) c = 8;
        addr_g[g] = ((wz * YL) * XL + n) * SSTR + ich * 16 + coff(c);
    }

    f32x4 acc[YT];
#pragma unroll
    for (int yy = 0; yy < YT; ++yy) acc[yy] = (f32x4){0.f, 0.f, 0.f, 0.f};

#pragma unroll
    for (int p = 0; p < YL; ++p) {
        bf16x8 F[5];
#pragma unroll
        for (int g = 0; g < 5; ++g)
            F[g] = *(const bf16x8*)(smem + addr_g[g] + p * (XL * SSTR));
#pragma unroll
        for (int tyk = 0; tyk < 3; ++tyk) {
            int yy = p - tyk;
            if (yy >= 0 && yy < YT) {
#pragma unroll
                for (int g = 0; g < 5; ++g)
                    acc[yy] = __builtin_amdgcn_mfma_f32_16x16x32_bf16(
                        __builtin_bit_cast(bf16x8, afr[tyk * 5 + g]), F[g], acc[yy], 0, 0, 0);
            }
        }
    }

    float4 bv = *(const float4*)(bias + b * OCn + hi * 4);
    int zo = z0 + wz;
#pragma unroll
    for (int yy = 0; yy < YT; ++yy) {
        int yo = y0 + yy;
        long obase = ((((long)b * OCn + hi * 4) * Dm + zo) * Dm + yo) * Dm + x0 + n;
#pragma unroll
        for (int r = 0; r < 4; ++r)
            out[obase + (long)r * PL] = acc[yy][r] + ((const float*)&bv)[r];
    }
}

extern "C" void kernel_launch(void* const* d_in, const int* in_sizes, int n_in,
                              void* d_out, int out_size, void* d_ws, size_t ws_size,
                              hipStream_t stream)
{
    const float* x   = (const float*)d_in[0];
    const float* hyp = (const float*)d_in[1];
    const float* Wk  = (const float*)d_in[2];
    const float* bk  = (const float*)d_in[3];
    const float* Wb  = (const float*)d_in[4];
    const float* bb  = (const float*)d_in[5];
    float* out = (float*)d_out;

    const size_t need = XT_TOTAL + 61440 + 256;
    if (ws_size >= need) {
        char* xT = (char*)d_ws;
        unsigned short* kwf = (unsigned short*)(xT + XT_TOTAL);
        float* biasp = (float*)(xT + XT_TOTAL + 61440);

        hipLaunchKernelGGL(prep_kernel, dim3(1665), dim3(256), 0, stream,
                           x, xT, hyp, Wk, bk, kwf, Wb, bb, biasp, 0);
        hipLaunchKernelGGL(conv_l2_kernel, dim3(BSn * 24 * 12 * 6), dim3(64), 0, stream,
                           xT, kwf, biasp, out);
    } else {
        // fallback: workspace too small for xT — hyper blocks only + r6 conv
        unsigned short* kwf = (unsigned short*)d_ws;
        float* biasp = (float*)((char*)d_ws + (size_t)BSn * FRAG_ELEMS * 2);

        hipLaunchKernelGGL(prep_kernel, dim3(121), dim3(256), 0, stream,
                           x, (char*)d_ws, hyp, Wk, bk, kwf, Wb, bb, biasp, 1544);
        hipLaunchKernelGGL(conv_fb_kernel, dim3(BSn * 6 * 12 * 24), dim3(256), 0, stream,
                           x, kwf, biasp, out);
    }
}